// Round 1
// baseline (70.235 us; speedup 1.0000x reference)
//
#include <hip/hip_runtime.h>

// out[b,k] = tanh( sum_{m in segment k} x[b,m] * w[m] ),  seg_ids sorted.
// Strategy: CSR-ify seg_ids via per-k binary search, then one thread per
// (b,k) output gathers its contiguous run. No atomics; x read exactly once.

__global__ void build_seg_ptr(const int* __restrict__ seg_ids,
                              int* __restrict__ seg_ptr,
                              int M, int K) {
    int k = blockIdx.x * blockDim.x + threadIdx.x;
    if (k > K) return;
    // lower_bound: first m with seg_ids[m] >= k
    int lo = 0, hi = M;
    while (lo < hi) {
        int mid = (lo + hi) >> 1;
        if (seg_ids[mid] < k) lo = mid + 1;
        else hi = mid;
    }
    seg_ptr[k] = lo;
}

__global__ void seg_gather_tanh(const float* __restrict__ x,
                                const float* __restrict__ w,
                                const int* __restrict__ seg_ptr,
                                float* __restrict__ out,
                                int M, int K) {
    int k = blockIdx.x * blockDim.x + threadIdx.x;
    int b = blockIdx.y;
    if (k >= K) return;
    int s = seg_ptr[k];
    int e = seg_ptr[k + 1];
    const float* xb = x + (size_t)b * (size_t)M;
    float sum = 0.0f;
    for (int m = s; m < e; ++m) {
        sum = fmaf(xb[m], w[m], sum);
    }
    out[(size_t)b * (size_t)K + k] = tanhf(sum);
}

extern "C" void kernel_launch(void* const* d_in, const int* in_sizes, int n_in,
                              void* d_out, int out_size, void* d_ws, size_t ws_size,
                              hipStream_t stream) {
    const float* x       = (const float*)d_in[0];
    const float* w       = (const float*)d_in[1];
    const int*   seg_ids = (const int*)d_in[2];
    float* out = (float*)d_out;

    const int M = in_sizes[1];           // 65536 (w length)
    const int B = in_sizes[0] / M;       // 256
    const int K = out_size / B;          // 4096

    int* seg_ptr = (int*)d_ws;           // K+1 ints in workspace

    build_seg_ptr<<<(K + 1 + 255) / 256, 256, 0, stream>>>(seg_ids, seg_ptr, M, K);

    dim3 grid((K + 255) / 256, B);
    seg_gather_tanh<<<grid, 256, 0, stream>>>(x, w, seg_ptr, out, M, K);
}

// Round 2
// 30.736 us; speedup vs baseline: 2.2851x; 2.2851x over previous
//
#include <hip/hip_runtime.h>

// out[b,k] = tanh( sum_{m in segment k} x[b,m] * w[m] ),  seg_ids sorted.
//
// R2 structure: CSR seg_ptr (binary search), then one block per
// (b, 256 consecutive segments). The block's m-range is contiguous:
//   [seg_ptr[k0], seg_ptr[k0+256])   (mean 4096 elems for this data)
// Phase 1: cooperatively load x*w for the range, coalesced, into LDS.
// Phase 2: thread t reduces segment k0+t serially from LDS, writes tanh.
// No atomics, no second pass, x read exactly once.

#define TPB 256      // threads per block == segments per block
#define CH  4608     // LDS chunk (floats) = 18 KB; covers mean+8 sigma range

__global__ void build_seg_ptr(const int* __restrict__ seg_ids,
                              int* __restrict__ seg_ptr,
                              int M, int K) {
    int k = blockIdx.x * blockDim.x + threadIdx.x;
    if (k > K) return;
    int lo = 0, hi = M;            // lower_bound: first m with seg_ids[m] >= k
    while (lo < hi) {
        int mid = (lo + hi) >> 1;
        if (seg_ids[mid] < k) lo = mid + 1;
        else hi = mid;
    }
    seg_ptr[k] = lo;
}

__global__ __launch_bounds__(TPB) void seg_reduce_tanh(
        const float* __restrict__ x,
        const float* __restrict__ w,
        const int* __restrict__ seg_ptr,
        float* __restrict__ out,
        int M, int K) {
    __shared__ float prod[CH];

    const int t  = threadIdx.x;
    const int k0 = blockIdx.x * TPB;
    const int b  = blockIdx.y;
    const float* __restrict__ xb = x + (size_t)b * (size_t)M;

    const int s   = seg_ptr[k0];          // uniform across block (broadcast)
    const int e   = seg_ptr[k0 + TPB];    // uniform
    const int a_t = seg_ptr[k0 + t];      // this thread's segment start
    const int b_t = seg_ptr[k0 + t + 1];  // and end

    float sum = 0.0f;
    for (int c = s; c < e; c += CH) {     // trip count uniform across block
        // ---- cooperative coalesced load + multiply into LDS ----
        #pragma unroll
        for (int j = 0; j < CH / TPB; ++j) {
            int m = c + t + j * TPB;
            float v = 0.0f;
            if (m < M) v = xb[m] * w[m];
            prod[t + j * TPB] = v;        // bank-conflict-free (stride 1)
        }
        __syncthreads();
        // ---- per-thread serial reduce of own segment from LDS ----
        int lo = max(a_t, c);
        int hi = min(b_t, c + CH);
        for (int m = lo; m < hi; ++m) sum += prod[m - c];
        __syncthreads();
    }
    out[(size_t)b * (size_t)K + k0 + t] = tanhf(sum);
}

extern "C" void kernel_launch(void* const* d_in, const int* in_sizes, int n_in,
                              void* d_out, int out_size, void* d_ws, size_t ws_size,
                              hipStream_t stream) {
    const float* x       = (const float*)d_in[0];
    const float* w       = (const float*)d_in[1];
    const int*   seg_ids = (const int*)d_in[2];
    float* out = (float*)d_out;

    const int M = in_sizes[1];           // 65536 (w length)
    const int B = in_sizes[0] / M;       // 256
    const int K = out_size / B;          // 4096

    int* seg_ptr = (int*)d_ws;           // K+1 ints in workspace

    build_seg_ptr<<<(K + 1 + 255) / 256, 256, 0, stream>>>(seg_ids, seg_ptr, M, K);

    dim3 grid(K / TPB, B);               // (16, 256) = 4096 blocks
    seg_reduce_tanh<<<grid, TPB, 0, stream>>>(x, w, seg_ptr, out, M, K);
}

// Round 3
// 25.643 us; speedup vs baseline: 2.7390x; 1.1986x over previous
//
#include <hip/hip_runtime.h>

// out[b,k] = tanh( sum_{m in segment k} x[b,m] * w[m] ),  seg_ids sorted.
//
// R3: CSR build via O(M) boundary scatter (coalesced, no binary search).
// Main kernel: one block per (b, 256 consecutive segments); block's m-range
// is contiguous. Phase 1: float4-vectorized coalesced load of x*w into LDS
// (window aligned down to 16B, guarded at range end -> exact fetch).
// Phase 2: thread t serially reduces segment k0+t from LDS, writes tanh.

#define TPB 256               // threads per block == segments per block
#define CH  5120              // LDS chunk (floats) = 20 KB -> 8 blocks/CU
#define VPT (CH / TPB / 4)    // float4 loads per thread per chunk = 5

__global__ void build_seg_ptr_scatter(const int* __restrict__ seg_ids,
                                      int* __restrict__ seg_ptr,
                                      int M, int K) {
    int m = blockIdx.x * blockDim.x + threadIdx.x;
    if (m >= M) return;
    int a  = seg_ids[m];
    int nb = (m + 1 < M) ? seg_ids[m + 1] : K;
    if (m == 0) {
        for (int k = 0; k <= a; ++k) seg_ptr[k] = 0;   // ids < seg 0..a start at 0
    }
    for (int k = a + 1; k <= nb; ++k) seg_ptr[k] = m + 1;
}

__global__ __launch_bounds__(TPB) void seg_reduce_tanh(
        const float* __restrict__ x,
        const float* __restrict__ w,
        const int* __restrict__ seg_ptr,
        float* __restrict__ out,
        int M, int K) {
    __shared__ float prod[CH];

    const int t  = threadIdx.x;
    const int k0 = blockIdx.x * TPB;
    const int b  = blockIdx.y;
    const float* __restrict__ xb = x + (size_t)b * (size_t)M;

    const int s    = seg_ptr[k0];          // block-uniform
    const int e    = seg_ptr[k0 + TPB];    // block-uniform
    const int base = s & ~3;               // 16B-aligned window start
    const int a_t  = seg_ptr[k0 + t];      // this thread's segment [a_t, b_t)
    const int b_t  = seg_ptr[k0 + t + 1];

    float sum = 0.0f;
    for (int c = base; c < e; c += CH) {   // trip count uniform (normally 1)
        const float4* __restrict__ x4 = reinterpret_cast<const float4*>(xb + c);
        const float4* __restrict__ w4 = reinterpret_cast<const float4*>(w + c);
        float4* __restrict__ p4 = reinterpret_cast<float4*>(prod);
        // ---- cooperative float4 load + multiply into LDS ----
        #pragma unroll
        for (int j = 0; j < VPT; ++j) {
            int idx = t + j * TPB;         // float4 index within chunk
            int mm  = c + idx * 4;         // float index in [base, base+CH)
            float4 v = make_float4(0.f, 0.f, 0.f, 0.f);
            if (mm < e) {                  // exact-range guard (mm%4==0, e<=M, M%4==0 -> safe)
                float4 xv = x4[idx];
                float4 wv = w4[idx];
                v.x = xv.x * wv.x; v.y = xv.y * wv.y;
                v.z = xv.z * wv.z; v.w = xv.w * wv.w;
            }
            p4[idx] = v;                   // ds_write_b128, conflict-free
        }
        __syncthreads();
        // ---- per-thread serial reduce of own segment from LDS ----
        int lo = max(a_t, c);
        int hi = min(b_t, c + CH);
        for (int m = lo; m < hi; ++m) sum += prod[m - c];
        __syncthreads();
    }
    out[(size_t)b * (size_t)K + k0 + t] = tanhf(sum);
}

extern "C" void kernel_launch(void* const* d_in, const int* in_sizes, int n_in,
                              void* d_out, int out_size, void* d_ws, size_t ws_size,
                              hipStream_t stream) {
    const float* x       = (const float*)d_in[0];
    const float* w       = (const float*)d_in[1];
    const int*   seg_ids = (const int*)d_in[2];
    float* out = (float*)d_out;

    const int M = in_sizes[1];           // 65536 (w length)
    const int B = in_sizes[0] / M;       // 256
    const int K = out_size / B;          // 4096

    int* seg_ptr = (int*)d_ws;           // K+1 ints in workspace

    build_seg_ptr_scatter<<<(M + 255) / 256, 256, 0, stream>>>(seg_ids, seg_ptr, M, K);

    dim3 grid(K / TPB, B);               // (16, 256) = 4096 blocks
    seg_reduce_tanh<<<grid, TPB, 0, stream>>>(x, w, seg_ptr, out, M, K);
}